// Round 9
// baseline (311.994 us; speedup 1.0000x reference)
//
#include <hip/hip_runtime.h>
#include <hip/hip_bf16.h>

#define BLOCK 1024
#define NREG  21

typedef __attribute__((ext_vector_type(8))) short short8;   // 8 bf16
typedef __attribute__((ext_vector_type(4))) float floatx4;
typedef __attribute__((ext_vector_type(4))) unsigned int uint4v;

// LDS map (bytes), total 73792 -> 2 blocks/CU:
//  [0,19584)        P f32[2][36][68]
//  [19584,37224)    V bf16[441][20]          ; c2out bf16[676][36] overlays [19584,68256)
//  [37232,73232)    pool bf16[900][20]
//  [73232,73360)    feat f32[32]
//  [73360,73600)    rowinfo[30], colinfo[30] (u32)
//  [73600,73768)    rep_row[21], rep_col[21] (int)
#define SMEM_P     0
#define SMEM_V     19584
#define SMEM_C2    19584
#define SMEM_POOL  37232
#define SMEM_FEAT  73232
#define SMEM_INFO  73360
#define SMEM_REP   73600
#define SMEM_TOTAL 73792

__device__ __forceinline__ int clamp05(int v) { return v < 0 ? 0 : (v > 5 ? 5 : v); }

__device__ __forceinline__ int band_id(int i, int e0, int e1, int e2, int e3) {
    int c = 0;
    #pragma unroll
    for (int k = 0; k < 5; ++k) {
        const int b0 = e0 - k, b1 = e1 - k, b2 = e2 - k, b3 = e3 - k;
        c += (b0 >= 1 && i >= b0);
        c += (b1 >= 1 && i >= b1);
        c += (b2 >= 1 && i >= b2);
        c += (b3 >= 1 && i >= b3);
    }
    return c;
}

// W2 [32 oc][64 ic][25 tap] f32 -> w2t bf16 [4 chunk][13 kt][32 n][32 k32]
// k32: tap = 2*kt + (k32>>4), ic = chunk*16 + (k32&15); tap 25 -> 0 (K pad)
__global__ __launch_bounds__(256) void w2_transform_kernel(
    const float* __restrict__ W2, __hip_bfloat16* __restrict__ w2t)
{
    const int idx = blockIdx.x * 256 + threadIdx.x;   // 53248 total
    if (idx < 53248) {
        const int k32 = idx & 31;
        const int n   = (idx >> 5) & 31;
        const int kt  = (idx >> 10) % 13;
        const int c   = (idx >> 10) / 13;
        const int tap = kt*2 + (k32 >> 4);
        const int ic  = c*16 + (k32 & 15);
        w2t[idx] = __float2bfloat16(tap < 25 ? W2[n*1600 + ic*25 + tap] : 0.f);
    }
}

__global__ __launch_bounds__(BLOCK, 8) void vsgnet_mfma_kernel(
    const float* __restrict__ bboxes,
    const int* __restrict__ obj_pairs,
    const int* __restrict__ fw_p,
    const int* __restrict__ fh_p,
    const float* __restrict__ W1,
    const float* __restrict__ b1,
    const __hip_bfloat16* __restrict__ w2t,
    const float* __restrict__ b2,
    const float* __restrict__ Wl,
    const float* __restrict__ bl,
    float* __restrict__ out)
{
    extern __shared__ __align__(16) char smem[];
    float* Pf = (float*)(smem + SMEM_P);
    float* feat = (float*)(smem + SMEM_FEAT);
    unsigned int* rowinfo = (unsigned int*)(smem + SMEM_INFO);
    unsigned int* colinfo = rowinfo + 30;
    int* rep_row = (int*)(smem + SMEM_REP);
    int* rep_col = rep_row + 21;

    const int tid = threadIdx.x;
    const int t = blockIdx.x;
    const int bidx = t >> 6;

    // --- uniform box coords ---
    const int pa = obj_pairs[2*t];
    const int pb = obj_pairs[2*t + 1];
    const float* Ab = bboxes + (bidx*36 + pa)*4;
    const float* Bb = bboxes + (bidx*36 + pb)*4;
    const float sfx = (float)(64.0 / (double)fw_p[0]);
    const float sfy = (float)(64.0 / (double)fh_p[0]);
    const int x0a = (int)floorf(Ab[0]*sfx);
    const int y0a = (int)floorf(Ab[1]*sfy);
    const int x1a = (int)floorf(Ab[2]*sfx);
    const int y1a = (int)floorf(Ab[3]*sfy);
    const int x0b = (int)floorf(Bb[0]*sfx);
    const int y0b = (int)floorf(Bb[1]*sfy);
    const int x1b = (int)floorf(Bb[2]*sfx);
    const int y1b = (int)floorf(Bb[3]*sfy);

    // --- phase A: rep init + P build (stride 68 f32) ---
    if (tid >= 256 && tid < 298) rep_row[tid - 256] = -1;
    if (tid < 128) {
        const int c = tid & 63;
        const int box = tid >> 6;
        const float* w = W1 + (c*2 + box)*25;
        float p[6][6];
        #pragma unroll
        for (int r = 0; r < 6; ++r) p[r][0] = 0.f;
        #pragma unroll
        for (int cc = 0; cc < 6; ++cc) p[0][cc] = 0.f;
        #pragma unroll
        for (int r = 1; r < 6; ++r)
            #pragma unroll
            for (int cc = 1; cc < 6; ++cc)
                p[r][cc] = w[(r-1)*5 + (cc-1)] + p[r-1][cc] + p[r][cc-1] - p[r-1][cc-1];
        float* Pd = Pf + (box*36)*68;
        #pragma unroll
        for (int r = 0; r < 6; ++r)
            #pragma unroll
            for (int cc = 0; cc < 6; ++cc)
                Pd[(r*6 + cc)*68 + c] = p[r][cc];
    }
    __syncthreads();

    // --- phase B: band tables ---
    if (tid < 30) {
        rowinfo[tid] = (unsigned)band_id(2*tid, y0a, y1a, y0b, y1b)
                     | ((unsigned)band_id(2*tid + 1, y0a, y1a, y0b, y1b) << 8);
    } else if (tid >= 32 && tid < 62) {
        const int j = tid - 32;
        colinfo[j] = (unsigned)band_id(2*j, x0a, x1a, x0b, x1b)
                   | ((unsigned)band_id(2*j + 1, x0a, x1a, x0b, x1b) << 8);
    } else if (tid >= 64 && tid < 124) {
        const int i = tid - 64;
        rep_row[band_id(i, y0a, y1a, y0b, y1b)] = i;
    } else if (tid >= 128 && tid < 188) {
        const int j = tid - 128;
        rep_col[band_id(j, x0a, x1a, x0b, x1b)] = j;
    }

    const int lane = tid & 63;
    const int wid  = tid >> 6;      // 16 waves
    const int kg   = lane >> 4;     // k-group: tap = kg>>1, ic-half = kg&1
    const int lr   = lane & 15;

    // M geometry: 43 tiles of 16 rows; wave w owns tiles {w, w+16, w+32(<43)}
    floatx4 acc[3][2];
    #pragma unroll
    for (int s = 0; s < 3; ++s) {
        acc[s][0] = (floatx4){0.f,0.f,0.f,0.f};
        acc[s][1] = (floatx4){0.f,0.f,0.f,0.f};
    }
    int abase[3];
    #pragma unroll
    for (int s = 0; s < 3; ++s) {
        const int mt = wid + 16*s;
        int m = mt*16 + lr; if (m > 675) m = 675;
        const int pi = m / 26;
        const int pj = m - pi*26;
        abase[s] = SMEM_POOL + (pi*30 + pj)*40 + (kg & 1)*16;
    }
    __syncthreads();   // P + tables ready

    // --- 4 chunks of 16 ic: V-build -> pool-build -> MFMA ---
    for (int c = 0; c < 4; ++c) {
        // V-build: V[combo][16ch] = sum of 2 box rect-sums + b1 (reads P corners directly)
        if (tid < 882) {
            const int g = tid & 1;               // 8-ch granule
            const int combo = tid >> 1;
            const int rb = combo / NREG;
            const int cb = combo - rb*NREG;
            const int i = rep_row[rb], j = rep_col[cb];
            if (i >= 0 && j >= 0) {
                const int r0a_ = clamp05(y0a - i), r1a_ = clamp05(y1a - i);
                const int r0b_ = clamp05(y0b - i), r1b_ = clamp05(y1b - i);
                const int c0a_ = clamp05(x0a - j), c1a_ = clamp05(x1a - j);
                const int c0b_ = clamp05(x0b - j), c1b_ = clamp05(x1b - j);
                const float* P0 = Pf + c*16 + g*8;
                const float* P1 = P0 + 36*68;
                #define CORN(Pq, r_, c_, h_) (*(const floatx4*)((Pq) + ((r_)*6 + (c_))*68 + (h_)*4))
                floatx4 vlo = CORN(P0,r1a_,c1a_,0) - CORN(P0,r0a_,c1a_,0)
                            - CORN(P0,r1a_,c0a_,0) + CORN(P0,r0a_,c0a_,0)
                            + CORN(P1,r1b_,c1b_,0) - CORN(P1,r0b_,c1b_,0)
                            - CORN(P1,r1b_,c0b_,0) + CORN(P1,r0b_,c0b_,0);
                floatx4 vhi = CORN(P0,r1a_,c1a_,1) - CORN(P0,r0a_,c1a_,1)
                            - CORN(P0,r1a_,c0a_,1) + CORN(P0,r0a_,c0a_,1)
                            + CORN(P1,r1b_,c1b_,1) - CORN(P1,r0b_,c1b_,1)
                            - CORN(P1,r1b_,c0b_,1) + CORN(P1,r0b_,c0b_,1);
                #undef CORN
                vlo += *(const floatx4*)(b1 + c*16 + g*8);
                vhi += *(const floatx4*)(b1 + c*16 + g*8 + 4);
                short8 o;
                #pragma unroll
                for (int e = 0; e < 4; ++e) o[e]   = (short)__bfloat16_as_ushort(__float2bfloat16(vlo[e]));
                #pragma unroll
                for (int e = 0; e < 4; ++e) o[4+e] = (short)__bfloat16_as_ushort(__float2bfloat16(vhi[e]));
                *(short8*)(smem + SMEM_V + combo*40 + g*16) = o;
            }
        }
        __syncthreads();

        // pool-build: pool[cell][16ch] = max of <=4 V combos
        for (int idx = tid; idx < 1800; idx += BLOCK) {
            const int g = idx & 1;
            const int cell = idx >> 1;
            const int pi = cell / 30;
            const int pj = cell - pi*30;
            const unsigned ri = rowinfo[pi], ci = colinfo[pj];
            const int rb0 = ri & 255, rb1 = (ri >> 8) & 255;
            const int cb0 = ci & 255, cb1 = (ci >> 8) & 255;
            const int go = g*16;
            const uint4v u00 = *(const uint4v*)(smem + SMEM_V + (rb0*NREG + cb0)*40 + go);
            const uint4v u01 = *(const uint4v*)(smem + SMEM_V + (rb0*NREG + cb1)*40 + go);
            const uint4v u10 = *(const uint4v*)(smem + SMEM_V + (rb1*NREG + cb0)*40 + go);
            const uint4v u11 = *(const uint4v*)(smem + SMEM_V + (rb1*NREG + cb1)*40 + go);
            uint4v o;
            #pragma unroll
            for (int u = 0; u < 4; ++u) {
                const float l0 = __uint_as_float(u00[u] << 16), h0 = __uint_as_float(u00[u] & 0xffff0000u);
                const float l1 = __uint_as_float(u01[u] << 16), h1 = __uint_as_float(u01[u] & 0xffff0000u);
                const float l2 = __uint_as_float(u10[u] << 16), h2 = __uint_as_float(u10[u] & 0xffff0000u);
                const float l3 = __uint_as_float(u11[u] << 16), h3 = __uint_as_float(u11[u] & 0xffff0000u);
                const float ml = fmaxf(fmaxf(l0, l1), fmaxf(l2, l3));
                const float mh = fmaxf(fmaxf(h0, h1), fmaxf(h2, h3));
                o[u] = (__float_as_uint(ml) >> 16) | (__float_as_uint(mh) & 0xffff0000u);
            }
            *(uint4v*)(smem + SMEM_POOL + cell*40 + go) = o;
        }
        __syncthreads();

        // MFMA: 13 k-steps of K=32 (2 taps x 16 ic); B from global w2t
        {
            const __hip_bfloat16* w2c = w2t + (c*13)*1024;
            #pragma unroll
            for (int kt = 0; kt < 13; ++kt) {
                const int tap0 = 2*kt;
                const int tap1 = (2*kt + 1 > 24) ? 24 : (2*kt + 1);   // kt=12: A reuses tap24 x B=0
                const int off0 = ((tap0/5)*30 + (tap0%5))*40;
                const int off1 = ((tap1/5)*30 + (tap1%5))*40;
                const int aoff = (kg & 2) ? off1 : off0;
                const short8 bf0 = *(const short8*)(w2c + kt*1024 + lr*32 + kg*8);
                const short8 bf1 = *(const short8*)(w2c + kt*1024 + (16 + lr)*32 + kg*8);
                const short8 a0 = *(const short8*)(smem + abase[0] + aoff);
                const short8 a1 = *(const short8*)(smem + abase[1] + aoff);
                acc[0][0] = __builtin_amdgcn_mfma_f32_16x16x32_bf16(a0, bf0, acc[0][0], 0, 0, 0);
                acc[0][1] = __builtin_amdgcn_mfma_f32_16x16x32_bf16(a0, bf1, acc[0][1], 0, 0, 0);
                acc[1][0] = __builtin_amdgcn_mfma_f32_16x16x32_bf16(a1, bf0, acc[1][0], 0, 0, 0);
                acc[1][1] = __builtin_amdgcn_mfma_f32_16x16x32_bf16(a1, bf1, acc[1][1], 0, 0, 0);
                if (wid < 11) {
                    const short8 a2 = *(const short8*)(smem + abase[2] + aoff);
                    acc[2][0] = __builtin_amdgcn_mfma_f32_16x16x32_bf16(a2, bf0, acc[2][0], 0, 0, 0);
                    acc[2][1] = __builtin_amdgcn_mfma_f32_16x16x32_bf16(a2, bf1, acc[2][1], 0, 0, 0);
                }
            }
        }
        __syncthreads();   // drain A-reads before next chunk overwrites V/pool
    }

    // --- epilogue: C (col=lane&15, row=(lane>>4)*4+reg) -> c2out[m][36] ---
    __hip_bfloat16* c2out = (__hip_bfloat16*)(smem + SMEM_C2);
    if (tid < 32) feat[tid] = 0.f;
    {
        const float b2v0 = b2[lr];
        const float b2v1 = b2[16 + lr];
        #pragma unroll
        for (int s = 0; s < 3; ++s) {
            const int mt = wid + 16*s;
            if (mt < 43) {
                #pragma unroll
                for (int r = 0; r < 4; ++r) {
                    const int m = mt*16 + kg*4 + r;
                    if (m < 676) {
                        c2out[m*36 + lr]      = __float2bfloat16(acc[s][0][r] + b2v0);
                        c2out[m*36 + 16 + lr] = __float2bfloat16(acc[s][1][r] + b2v1);
                    }
                }
            }
        }
    }
    __syncthreads();

    // --- pool2 2x2 + mean(13x13) ---
    {
        const int oc  = tid & 31;
        const int grp = tid >> 5;
        float sum = 0.f;
        for (int cell = grp; cell < 169; cell += 32) {
            const int ci = cell / 13;
            const int cj = cell - ci*13;
            const __hip_bfloat16* q = c2out + ((ci*2)*26 + cj*2)*36 + oc;
            const float v0 = __bfloat162float(q[0]);
            const float v1 = __bfloat162float(q[36]);
            const float v2 = __bfloat162float(q[936]);
            const float v3 = __bfloat162float(q[972]);
            sum += fmaxf(fmaxf(v0, v1), fmaxf(v2, v3));
        }
        atomicAdd(&feat[oc], sum * (1.0f/169.0f));
    }
    __syncthreads();

    // --- linear 32 -> 512 + ReLU ---
    if (tid < 512) {
        float s = bl[tid];
        #pragma unroll
        for (int ic = 0; ic < 32; ++ic)
            s = fmaf(feat[ic], Wl[ic*512 + tid], s);
        out[(size_t)t*512 + tid] = fmaxf(s, 0.f);
    }
}

extern "C" void kernel_launch(void* const* d_in, const int* in_sizes, int n_in,
                              void* d_out, int out_size, void* d_ws, size_t ws_size,
                              hipStream_t stream) {
    const float* bboxes    = (const float*)d_in[0];
    const int*   obj_pairs = (const int*)d_in[1];
    const int*   fw        = (const int*)d_in[3];
    const int*   fh        = (const int*)d_in[4];
    const float* W1        = (const float*)d_in[5];
    const float* b1        = (const float*)d_in[6];
    const float* W2        = (const float*)d_in[7];
    const float* b2        = (const float*)d_in[8];
    const float* Wl        = (const float*)d_in[9];
    const float* bl        = (const float*)d_in[10];
    float* out = (float*)d_out;
    __hip_bfloat16* w2t = (__hip_bfloat16*)d_ws;    // 106496 B scratch

    w2_transform_kernel<<<dim3(208), dim3(256), 0, stream>>>(W2, w2t);

    hipFuncSetAttribute((const void*)vsgnet_mfma_kernel,
                        hipFuncAttributeMaxDynamicSharedMemorySize, SMEM_TOTAL);
    vsgnet_mfma_kernel<<<dim3(1024), dim3(BLOCK), SMEM_TOTAL, stream>>>(
        bboxes, obj_pairs, fw, fh, W1, b1, w2t, b2, Wl, bl, out);
}